// Round 5
// baseline (319.395 us; speedup 1.0000x reference)
//
#include <hip/hip_runtime.h>

#define DI __device__ __forceinline__

typedef float  f32x2  __attribute__((ext_vector_type(2)));
typedef float  f32x4  __attribute__((ext_vector_type(4)));
typedef float  f32x16 __attribute__((ext_vector_type(16)));
typedef __bf16 bf16x8 __attribute__((ext_vector_type(8)));
typedef unsigned u32x2 __attribute__((ext_vector_type(2)));
typedef unsigned u32x4 __attribute__((ext_vector_type(4)));

static constexpr int TB   = 2048;   // tokens per batch
static constexpr int NTOK = 8192;   // 4 * 2048
static constexpr int EMB  = 1024;
static constexpr int FQKV = 3072;

// RTNE float -> bf16 bits
DI unsigned short f2bf(float f) {
  union { float f; unsigned u; } v; v.f = f;
  unsigned r = v.u + 0x7FFFu + ((v.u >> 16) & 1u);
  return (unsigned short)(r >> 16);
}

DI unsigned pack2bf(float a, float b) {
#if __has_builtin(__builtin_amdgcn_cvt_pk_bf16_f32)
  typedef __bf16 bf16x2 __attribute__((ext_vector_type(2)));
  bf16x2 r = __builtin_amdgcn_cvt_pk_bf16_f32(a, b);
  return __builtin_bit_cast(unsigned, r);
#else
  unsigned ua = __builtin_bit_cast(unsigned, a) + 0x8000u;
  unsigned ub = __builtin_bit_cast(unsigned, b) + 0x8000u;
  return __builtin_amdgcn_perm(ub, ua, 0x07060302u);
#endif
}

DI void plswap(unsigned& a, unsigned& b) {
#if __has_builtin(__builtin_amdgcn_permlane32_swap)
  u32x2 r = __builtin_amdgcn_permlane32_swap(a, b, false, false);
  a = r.x; b = r.y;
#else
  const bool hi = (threadIdx.x & 32) != 0;
  unsigned ax = (unsigned)__shfl_xor((int)a, 32);
  unsigned bx = (unsigned)__shfl_xor((int)b, 32);
  unsigned na = hi ? bx : a;
  unsigned nb = hi ? b : ax;
  a = na; b = nb;
#endif
}

DI bf16x8 frag4(unsigned a, unsigned b, unsigned c, unsigned d) {
  u32x4 u = {a, b, c, d};
  return __builtin_bit_cast(bf16x8, u);
}

// async global->LDS, 16B per lane; LDS dest = wave-uniform base + lane*16
DI void gload16(const void* g, void* l) {
  __builtin_amdgcn_global_load_lds(
      (__attribute__((address_space(1))) void*)(g),
      (__attribute__((address_space(3))) void*)(l), 16, 0, 0);
}

DI void wait_vm4() { asm volatile("s_waitcnt vmcnt(4)" ::: "memory"); }
DI void wait_vm0() { asm volatile("s_waitcnt vmcnt(0)" ::: "memory"); }
DI void rbar()     { __builtin_amdgcn_s_barrier(); }
DI void sfence()   { __builtin_amdgcn_sched_barrier(0); }

// ---------------- fp32 -> bf16 conversion for x, w_qkv, w_out ----------------
__global__ __launch_bounds__(256)
void cvt_kernel(const float4* __restrict__ x, const float4* __restrict__ wq,
                const float4* __restrict__ wo,
                ushort4* __restrict__ xb, ushort4* __restrict__ wqb,
                ushort4* __restrict__ wob) {
  const int i  = blockIdx.x * 256 + threadIdx.x;
  const int nx = NTOK * EMB / 4;
  const int nq = FQKV * EMB / 4;
  float4 v; ushort4* dst;
  if (i < nx)           { v = x[i];           dst = xb  + i; }
  else if (i < nx + nq) { v = wq[i - nx];     dst = wqb + (i - nx); }
  else                  { v = wo[i - nx - nq]; dst = wob + (i - nx - nq); }
  ushort4 p;
  p.x = f2bf(v.x); p.y = f2bf(v.y); p.z = f2bf(v.z); p.w = f2bf(v.w);
  *dst = p;
}

// ---------------- 256x256 bf16 GEMM, 16 waves, 2-phase counted-vmcnt --------
// r4 post-mortem: three schedule structures (single-buf, 2-phase, 4-phase/
// 2-deep) ALL give ~90us QKV with MfmaUtil 22 / VALU 13 / conflicts 0 /
// HBM 16% — nothing busy, pure latency exposure at 8 waves/CU (2/SIMD,
// 1 block/CU from 128KB LDS). Fix occupancy, not schedule: 16 waves (1024
// threads), per-wave 64x64 output -> acc[4][4]=64 VGPR, total <=128 so the
// block fits 4 waves/SIMD = 16 waves/CU (2x the overlap slack).
// Staging/swizzle/pipeline cadence identical to the r2-verified gemm256:
// granule g of row r holds src granule g^(r&7) (measured 0 conflicts);
// stage(t+1) -> vmcnt(4) -> bar -> ds_read+MFMA -> bar.
// MODE 0: QKV epilogue (qk scaled / vT transposed).  MODE 1: split-K
// out-projection: A/Bt offset by blockIdx.z*KLEN, f32 atomicAdd into outp.
template <int MODE>
__global__ __launch_bounds__(1024)
void gemm16w(const unsigned short* __restrict__ A,
             const unsigned short* __restrict__ Bt,
             const int Kstride, const int Klen,
             unsigned short* __restrict__ qk,
             unsigned short* __restrict__ vT,
             float* __restrict__ outp) {
  __shared__ unsigned short sA[2][256 * 64];   // 32KB each
  __shared__ unsigned short sB[2][256 * 64];
  const int tid  = threadIdx.x;
  const int w    = tid >> 6;          // 0..15
  const int l    = tid & 63;
  const int quad = l >> 4;
  const int lr   = l & 15;
  // XCD-aware bijective swizzle on (x,y); nwg = 384 (mode0) / 128 (mode1),
  // both % 8 == 0
  const int nwg  = gridDim.x * gridDim.y;
  const int orig = blockIdx.y * gridDim.x + blockIdx.x;
  const int swz  = (orig & 7) * (nwg >> 3) + (orig >> 3);
  const int n0   = (swz % gridDim.x) * 256;
  const int m0   = (swz / gridDim.x) * 256;
  const int wm   = (w >> 2) * 64;     // wave row offset in tile
  const int wn   = (w & 3) * 64;      // wave col offset in tile
  const int kofs = (MODE == 1) ? blockIdx.z * Klen : 0;

  f32x4 acc[4][4];
#pragma unroll
  for (int i = 0; i < 4; ++i)
#pragma unroll
    for (int j = 0; j < 4; ++j) acc[i][j] = {0.f, 0.f, 0.f, 0.f};

  // staging: per K-tile (256x64 each of A,B = 64KB) each thread does
  // 2 A-loads + 2 B-loads (16B). One gload16 instr covers 8 rows x 8
  // granules; wave w covers rows [w*16, w*16+16) via jj=0,1.
  const int srow8 = l >> 3;                 // 0..7
  const int gsw   = ((l & 7) ^ srow8) * 8;  // pre-swizzled source granule
  const unsigned short* gA0 = A  + (long)(m0 + w * 16 + srow8) * Kstride + kofs + gsw;
  const unsigned short* gB0 = Bt + (long)(n0 + w * 16 + srow8) * Kstride + kofs + gsw;

  const int NT = Klen >> 6;   // K-tiles of 64

#define STAGE16(buf, kk)                                                       \
  do {                                                                         \
    _Pragma("unroll")                                                          \
    for (int jj = 0; jj < 2; ++jj) {                                           \
      gload16(gA0 + (long)jj * 8 * Kstride + (kk), &sA[buf][(w * 16 + jj * 8) * 64]); \
      gload16(gB0 + (long)jj * 8 * Kstride + (kk), &sB[buf][(w * 16 + jj * 8) * 64]); \
    }                                                                          \
  } while (0)

  STAGE16(0, 0);

  for (int t = 0; t < NT; ++t) {
    const int cur = t & 1;
    if (t + 1 < NT) { STAGE16(cur ^ 1, (t + 1) * 64); wait_vm4(); }
    else            { wait_vm0(); }
    sfence();
    rbar();          // tile t visible in buf[cur]
    sfence();
    const unsigned short* aS = &sA[cur][0];
    const unsigned short* bS = &sB[cur][0];
#pragma unroll
    for (int ks = 0; ks < 2; ++ks) {
      bf16x8 bfr[4];
#pragma unroll
      for (int nf = 0; nf < 4; ++nf) {
        const int r = wn + nf * 16 + lr;
        bfr[nf] = *(const bf16x8*)(bS + r * 64 + (((ks * 4 + quad) ^ (r & 7)) * 8));
      }
      __builtin_amdgcn_s_setprio(1);
#pragma unroll
      for (int m = 0; m < 4; ++m) {
        const int ra = wm + m * 16 + lr;
        const bf16x8 af = *(const bf16x8*)(aS + ra * 64 + (((ks * 4 + quad) ^ (ra & 7)) * 8));
#pragma unroll
        for (int nf = 0; nf < 4; ++nf)
          acc[m][nf] = __builtin_amdgcn_mfma_f32_16x16x32_bf16(af, bfr[nf],
                                                               acc[m][nf], 0, 0, 0);
      }
      __builtin_amdgcn_s_setprio(0);
    }
    sfence();
    rbar();          // reads of buf[cur] done before it is re-staged
  }
#undef STAGE16

  if (MODE == 0) {
    if (n0 < 2048) {
      const float qs = (n0 < 1024) ? 0.18033688011112042f : 1.0f;
#pragma unroll
      for (int m = 0; m < 4; ++m) {
        const int row = m0 + wm + m * 16 + quad * 4;
#pragma unroll
        for (int nf = 0; nf < 4; ++nf) {
          const int col = n0 + wn + nf * 16 + lr;
#pragma unroll
          for (int r = 0; r < 4; ++r)
            qk[(long)(row + r) * 2048 + col] = f2bf(acc[m][nf][r] * qs);
        }
      }
    } else {
#pragma unroll
      for (int m = 0; m < 4; ++m) {
        const int tok = m0 + wm + m * 16 + quad * 4;
        const int bb  = tok >> 11, tt = tok & 2047;
#pragma unroll
        for (int nf = 0; nf < 4; ++nf) {
          const int fv = n0 - 2048 + wn + nf * 16 + lr;  // h*64+d
          ushort4 p;
          p.x = f2bf(acc[m][nf][0]); p.y = f2bf(acc[m][nf][1]);
          p.z = f2bf(acc[m][nf][2]); p.w = f2bf(acc[m][nf][3]);
          *(ushort4*)(vT + ((long)(bb * 1024 + fv)) * 2048 + tt) = p;
        }
      }
    }
  } else {
    // split-K: accumulate into pre-zeroed f32 output
#pragma unroll
    for (int m = 0; m < 4; ++m) {
      const int row = m0 + wm + m * 16 + quad * 4;
#pragma unroll
      for (int nf = 0; nf < 4; ++nf) {
        const int col = n0 + wn + nf * 16 + lr;
#pragma unroll
        for (int r = 0; r < 4; ++r)
          atomicAdd(&outp[(long)(row + r) * 1024 + col], acc[m][nf][r]);
      }
    }
  }
}

// ---------------- flash attention (unchanged: 90.4us, 760 TF) ---------------
__global__ __launch_bounds__(256, 4)
void attn_kernel(const unsigned short* __restrict__ qk,
                 const unsigned short* __restrict__ vT,
                 unsigned short* __restrict__ attnb) {
  __shared__ unsigned short sK[2][64 * 64];
  __shared__ unsigned short sV[2][64 * 64];
  const int tid = threadIdx.x;
  const int w   = tid >> 6;
  const int l   = tid & 63;
  const int l31 = l & 31;
  const int lh  = l >> 5;
  const int h8  = lh * 8;
  const int bh  = blockIdx.x;
  const int hh  = bh & 15;
  const long tokbase = (long)(bh >> 4) * TB;
  const int qbase = blockIdx.y * 128 + w * 32;

  bf16x8 qf[4];
  {
    const unsigned short* qptr = qk + (tokbase + qbase + l31) * 2048 + hh * 64 + h8;
#pragma unroll
    for (int s = 0; s < 4; ++s) qf[s] = *(const bf16x8*)(qptr + s * 16);
  }

  const int srow = l >> 3;
  const int g    = (l & 7) ^ srow;
  const unsigned short* kbase =
      qk + (tokbase + w * 16 + srow) * 2048 + 1024 + hh * 64 + g * 8;
  const unsigned short* vbase =
      vT + ((long)bh * 64 + w * 16 + srow) * 2048 + g * 8;

  f32x16 oacc[2] = {{}, {}};
  f32x2 lp2 = {0.f, 0.f};

  gload16(kbase,            &sK[0][(w * 16 + 0) * 64]);
  gload16(kbase + 8 * 2048, &sK[0][(w * 16 + 8) * 64]);
  gload16(vbase,            &sV[0][(w * 16 + 0) * 64]);
  gload16(vbase + 8 * 2048, &sV[0][(w * 16 + 8) * 64]);

  for (int t = 0; t < 32; ++t) {
    const int buf = t & 1;
    if (t + 1 < 32) {
      const int k0 = (t + 1) * 64;
      const int nb = buf ^ 1;
      gload16(kbase + (long)k0 * 2048,            &sK[nb][(w * 16 + 0) * 64]);
      gload16(kbase + (long)k0 * 2048 + 8 * 2048, &sK[nb][(w * 16 + 8) * 64]);
      gload16(vbase + k0,                         &sV[nb][(w * 16 + 0) * 64]);
      gload16(vbase + k0 + 8 * 2048,              &sV[nb][(w * 16 + 8) * 64]);
      wait_vm4();
    } else {
      wait_vm0();
    }
    sfence();
    rbar();
    sfence();
    const unsigned short* bK = sK[buf];
    const unsigned short* bV = sV[buf];

#pragma unroll
    for (int G = 0; G < 2; ++G) {
      f32x16 sacc = {};
      __builtin_amdgcn_s_setprio(1);
#pragma unroll
      for (int s = 0; s < 4; ++s) {
        const int key = G * 32 + l31;
        const int p   = (s * 2 + lh) ^ (key & 7);
        const bf16x8 kf = *(const bf16x8*)(bK + key * 64 + p * 8);
        sacc = __builtin_amdgcn_mfma_f32_32x32x16_bf16(kf, qf[s], sacc, 0, 0, 0);
      }
      __builtin_amdgcn_s_setprio(0);
      float e[16];
#pragma unroll
      for (int i = 0; i < 16; ++i) e[i] = __builtin_amdgcn_exp2f(sacc[i]);
#pragma unroll
      for (int i = 0; i < 8; ++i) {
        f32x2 pr = {e[2 * i], e[2 * i + 1]};
        lp2 += pr;
      }
      unsigned d[8];
#pragma unroll
      for (int i = 0; i < 8; ++i) d[i] = pack2bf(e[2 * i], e[2 * i + 1]);
      plswap(d[0], d[2]); plswap(d[1], d[3]);
      plswap(d[4], d[6]); plswap(d[5], d[7]);
      bf16x8 pp[2];
      pp[0] = frag4(d[0], d[1], d[2], d[3]);
      pp[1] = frag4(d[4], d[5], d[6], d[7]);
      __builtin_amdgcn_s_setprio(1);
#pragma unroll
      for (int sub = 0; sub < 2; ++sub) {
        const int gt  = (G * 2 + sub) * 2 + lh;
        const int d0r = l31, d1r = 32 + l31;
        const bf16x8 vf0 = *(const bf16x8*)(bV + d0r * 64 + ((gt ^ (d0r & 7))) * 8);
        const bf16x8 vf1 = *(const bf16x8*)(bV + d1r * 64 + ((gt ^ (d1r & 7))) * 8);
        oacc[0] = __builtin_amdgcn_mfma_f32_32x32x16_bf16(pp[sub], vf0, oacc[0], 0, 0, 0);
        oacc[1] = __builtin_amdgcn_mfma_f32_32x32x16_bf16(pp[sub], vf1, oacc[1], 0, 0, 0);
      }
      __builtin_amdgcn_s_setprio(0);
    }
    sfence();
    rbar();
  }

  const float lp = lp2.x + lp2.y;
  const float fs = lp + __shfl_xor(lp, 32);
  const float rc = 1.0f / fs;
#pragma unroll
  for (int r = 0; r < 16; ++r) {
    const int row = (r & 3) + 8 * (r >> 2) + 4 * lh;
    const float sc = __shfl(rc, row);
    const long base = (tokbase + qbase + row) * 1024 + hh * 64;
    attnb[base + l31]      = f2bf(oacc[0][r] * sc);
    attnb[base + 32 + l31] = f2bf(oacc[1][r] * sc);
  }
}

// ---------------------------------------------------------------------------
extern "C" void kernel_launch(void* const* d_in, const int* in_sizes, int n_in,
                              void* d_out, int out_size, void* d_ws, size_t ws_size,
                              hipStream_t stream) {
  const float* x    = (const float*)d_in[0];
  const float* wqkv = (const float*)d_in[1];
  const float* wout = (const float*)d_in[2];
  float* outp = (float*)d_out;

  unsigned short* xb    = (unsigned short*)d_ws;          // 8192*1024
  unsigned short* wqkvb = xb    + (long)NTOK * EMB;       // 3072*1024
  unsigned short* woutb = wqkvb + (long)FQKV * EMB;       // 1024*1024
  unsigned short* qkb   = woutb + (long)EMB * EMB;        // 8192*2048 (Q|K)
  unsigned short* vTb   = qkb   + (long)NTOK * 2048;      // 4*16*64*2048
  unsigned short* attnb = vTb   + (long)4 * 16 * 64 * TB; // 8192*1024

  cvt_kernel<<<12288, 256, 0, stream>>>(
      (const float4*)x, (const float4*)wqkv, (const float4*)wout,
      (ushort4*)xb, (ushort4*)wqkvb, (ushort4*)woutb);

  // QKV projection: 16-wave 256^2, 384 blocks
  gemm16w<0><<<dim3(12, 32), 1024, 0, stream>>>(
      xb, wqkvb, EMB, EMB, qkb, vTb, nullptr);

  attn_kernel<<<dim3(64, 16), 256, 0, stream>>>(qkb, vTb, attnb);

  // output projection: split-K x2 (K=512 each), f32 atomic accumulate
  hipMemsetAsync(outp, 0, (size_t)NTOK * EMB * sizeof(float), stream);
  gemm16w<1><<<dim3(4, 32, 2), 1024, 0, stream>>>(
      attnb, woutb, EMB, 512, nullptr, nullptr, outp);
}

// Round 6
// 269.367 us; speedup vs baseline: 1.1857x; 1.1857x over previous
//
#include <hip/hip_runtime.h>

#define DI __device__ __forceinline__

typedef float  f32x2  __attribute__((ext_vector_type(2)));
typedef float  f32x4  __attribute__((ext_vector_type(4)));
typedef float  f32x16 __attribute__((ext_vector_type(16)));
typedef __bf16 bf16x8 __attribute__((ext_vector_type(8)));
typedef unsigned u32x2 __attribute__((ext_vector_type(2)));
typedef unsigned u32x4 __attribute__((ext_vector_type(4)));

static constexpr int TB   = 2048;   // tokens per batch
static constexpr int NTOK = 8192;   // 4 * 2048
static constexpr int EMB  = 1024;
static constexpr int FQKV = 3072;

// RTNE float -> bf16 bits
DI unsigned short f2bf(float f) {
  union { float f; unsigned u; } v; v.f = f;
  unsigned r = v.u + 0x7FFFu + ((v.u >> 16) & 1u);
  return (unsigned short)(r >> 16);
}

DI unsigned pack2bf(float a, float b) {
#if __has_builtin(__builtin_amdgcn_cvt_pk_bf16_f32)
  typedef __bf16 bf16x2 __attribute__((ext_vector_type(2)));
  bf16x2 r = __builtin_amdgcn_cvt_pk_bf16_f32(a, b);
  return __builtin_bit_cast(unsigned, r);
#else
  unsigned ua = __builtin_bit_cast(unsigned, a) + 0x8000u;
  unsigned ub = __builtin_bit_cast(unsigned, b) + 0x8000u;
  return __builtin_amdgcn_perm(ub, ua, 0x07060302u);
#endif
}

DI void plswap(unsigned& a, unsigned& b) {
#if __has_builtin(__builtin_amdgcn_permlane32_swap)
  u32x2 r = __builtin_amdgcn_permlane32_swap(a, b, false, false);
  a = r.x; b = r.y;
#else
  const bool hi = (threadIdx.x & 32) != 0;
  unsigned ax = (unsigned)__shfl_xor((int)a, 32);
  unsigned bx = (unsigned)__shfl_xor((int)b, 32);
  unsigned na = hi ? bx : a;
  unsigned nb = hi ? b : ax;
  a = na; b = nb;
#endif
}

DI bf16x8 frag4(unsigned a, unsigned b, unsigned c, unsigned d) {
  u32x4 u = {a, b, c, d};
  return __builtin_bit_cast(bf16x8, u);
}

// async global->LDS, 16B per lane; LDS dest = wave-uniform base + lane*16
DI void gload16(const void* g, void* l) {
  __builtin_amdgcn_global_load_lds(
      (__attribute__((address_space(1))) void*)(g),
      (__attribute__((address_space(3))) void*)(l), 16, 0, 0);
}

DI void wait_vm4() { asm volatile("s_waitcnt vmcnt(4)" ::: "memory"); }
DI void wait_vm0() { asm volatile("s_waitcnt vmcnt(0)" ::: "memory"); }
DI void rbar()     { __builtin_amdgcn_s_barrier(); }
DI void sfence()   { __builtin_amdgcn_sched_barrier(0); }

// barrier with guaranteed pre-drain of this wave's outstanding DMA ops
DI void syncdrain() {
  __builtin_amdgcn_s_waitcnt(0);
  __syncthreads();
}

// ---------------- fp32 -> bf16 conversion for x, w_qkv, w_out ----------------
__global__ __launch_bounds__(256)
void cvt_kernel(const float4* __restrict__ x, const float4* __restrict__ wq,
                const float4* __restrict__ wo,
                ushort4* __restrict__ xb, ushort4* __restrict__ wqb,
                ushort4* __restrict__ wob) {
  const int i  = blockIdx.x * 256 + threadIdx.x;
  const int nx = NTOK * EMB / 4;
  const int nq = FQKV * EMB / 4;
  float4 v; ushort4* dst;
  if (i < nx)           { v = x[i];           dst = xb  + i; }
  else if (i < nx + nq) { v = wq[i - nx];     dst = wqb + (i - nx); }
  else                  { v = wo[i - nx - nq]; dst = wob + (i - nx - nq); }
  ushort4 p;
  p.x = f2bf(v.x); p.y = f2bf(v.y); p.z = f2bf(v.z); p.w = f2bf(v.w);
  *dst = p;
}

// ---------------- 128x128 bf16 GEMM, C = A * Bt^T (both row-major [.,K]) ----
// r5 post-mortem: every 256^2 / 1-block-per-CU restructure (2-phase, counted
// vmcnt, 4-phase/2-deep, 16-wave) landed at ~570 TF or worse; the ORIGINAL
// single-buffered 128^2 remains the best-measured config (274.2us total).
// Mechanism: at 16KB LDS / ~110 VGPR, 4 independent blocks co-reside per CU
// and implicit cross-block overlap (m114) hides the per-tile drain — the
// thing all 1-block/CU variants destroyed. This round keeps the structure
// verbatim and adds only: (1) __launch_bounds__(256,4) to GUARANTEE <=128
// VGPR -> 4 blocks/CU; (2) bijective XCD swizzle (nwg 1536/512, both %8==0).
template <int MODE>
__global__ __launch_bounds__(256, 4)
void gemm_bt(const unsigned short* __restrict__ A,
             const unsigned short* __restrict__ Bt,
             const int K,
             unsigned short* __restrict__ qk,
             unsigned short* __restrict__ vT,
             float* __restrict__ outp) {
  __shared__ unsigned short sA[128 * 32];
  __shared__ unsigned short sB[128 * 32];
  const int tid  = threadIdx.x;
  const int w    = tid >> 6;
  const int l    = tid & 63;
  const int quad = l >> 4;
  const int lr   = l & 15;
  // XCD-aware bijective swizzle of linear block id
  const int nwg  = gridDim.x * gridDim.y;
  const int orig = blockIdx.y * gridDim.x + blockIdx.x;
  const int swzb = (orig & 7) * (nwg >> 3) + (orig >> 3);
  const int n0   = (swzb % gridDim.x) * 128;
  const int m0   = (swzb / gridDim.x) * 128;
  const int wm   = (w >> 1) * 64;
  const int wn   = (w & 1) * 64;

  f32x4 acc[4][4];
#pragma unroll
  for (int i = 0; i < 4; ++i)
#pragma unroll
    for (int j = 0; j < 4; ++j) acc[i][j] = {0.f, 0.f, 0.f, 0.f};

  const int srow = l >> 2;
  const int sg   = (l & 3) ^ ((l >> 3) & 3);
  const unsigned short* gA = A  + (long)(m0 + w * 32 + srow) * K + sg * 8;
  const unsigned short* gB = Bt + (long)(n0 + w * 32 + srow) * K + sg * 8;
  unsigned short* lA = sA + w * 1024;
  unsigned short* lB = sB + w * 1024;
  const int swz = (lr >> 1) & 3;

  for (int k0 = 0; k0 < K; k0 += 32) {
    gload16(gA + k0,          lA);
    gload16(gA + k0 + 16 * K, lA + 512);
    gload16(gB + k0,          lB);
    gload16(gB + k0 + 16 * K, lB + 512);
    syncdrain();
    bf16x8 af[4], bfr[4];
#pragma unroll
    for (int rt = 0; rt < 4; ++rt)
      af[rt] = *(const bf16x8*)(sA + (wm + rt * 16 + lr) * 32 + (quad ^ swz) * 8);
#pragma unroll
    for (int ct = 0; ct < 4; ++ct)
      bfr[ct] = *(const bf16x8*)(sB + (wn + ct * 16 + lr) * 32 + (quad ^ swz) * 8);
#pragma unroll
    for (int rt = 0; rt < 4; ++rt)
#pragma unroll
      for (int ct = 0; ct < 4; ++ct)
        acc[rt][ct] = __builtin_amdgcn_mfma_f32_16x16x32_bf16(af[rt], bfr[ct],
                                                              acc[rt][ct], 0, 0, 0);
    __syncthreads();
  }

  if (MODE == 0) {
    if (n0 < 2048) {
      const float qs = (n0 < 1024) ? 0.18033688011112042f : 1.0f;
#pragma unroll
      for (int rt = 0; rt < 4; ++rt) {
        const int row = m0 + wm + rt * 16 + quad * 4;
#pragma unroll
        for (int ct = 0; ct < 4; ++ct) {
          const int col = n0 + wn + ct * 16 + lr;
#pragma unroll
          for (int r = 0; r < 4; ++r)
            qk[(long)(row + r) * 2048 + col] = f2bf(acc[rt][ct][r] * qs);
        }
      }
    } else {
#pragma unroll
      for (int rt = 0; rt < 4; ++rt) {
        const int tok = m0 + wm + rt * 16 + quad * 4;
        const int bb  = tok >> 11, tt = tok & 2047;
#pragma unroll
        for (int ct = 0; ct < 4; ++ct) {
          const int fv = n0 - 2048 + wn + ct * 16 + lr;  // h*64+d
          ushort4 p;
          p.x = f2bf(acc[rt][ct][0]); p.y = f2bf(acc[rt][ct][1]);
          p.z = f2bf(acc[rt][ct][2]); p.w = f2bf(acc[rt][ct][3]);
          *(ushort4*)(vT + ((long)(bb * 1024 + fv)) * 2048 + tt) = p;
        }
      }
    }
  } else {
#pragma unroll
    for (int rt = 0; rt < 4; ++rt) {
      const int row = m0 + wm + rt * 16 + quad * 4;
#pragma unroll
      for (int ct = 0; ct < 4; ++ct) {
        const int col = n0 + wn + ct * 16 + lr;
#pragma unroll
        for (int r = 0; r < 4; ++r)
          outp[(long)(row + r) * 1024 + col] = acc[rt][ct][r];
      }
    }
  }
}

// ---------------- flash attention (measured 90.4us across r2-r5, unchanged) -
__global__ __launch_bounds__(256, 4)
void attn_kernel(const unsigned short* __restrict__ qk,
                 const unsigned short* __restrict__ vT,
                 unsigned short* __restrict__ attnb) {
  __shared__ unsigned short sK[2][64 * 64];
  __shared__ unsigned short sV[2][64 * 64];
  const int tid = threadIdx.x;
  const int w   = tid >> 6;
  const int l   = tid & 63;
  const int l31 = l & 31;
  const int lh  = l >> 5;
  const int h8  = lh * 8;
  const int bh  = blockIdx.x;
  const int hh  = bh & 15;
  const long tokbase = (long)(bh >> 4) * TB;
  const int qbase = blockIdx.y * 128 + w * 32;

  bf16x8 qf[4];
  {
    const unsigned short* qptr = qk + (tokbase + qbase + l31) * 2048 + hh * 64 + h8;
#pragma unroll
    for (int s = 0; s < 4; ++s) qf[s] = *(const bf16x8*)(qptr + s * 16);
  }

  const int srow = l >> 3;
  const int g    = (l & 7) ^ srow;
  const unsigned short* kbase =
      qk + (tokbase + w * 16 + srow) * 2048 + 1024 + hh * 64 + g * 8;
  const unsigned short* vbase =
      vT + ((long)bh * 64 + w * 16 + srow) * 2048 + g * 8;

  f32x16 oacc[2] = {{}, {}};
  f32x2 lp2 = {0.f, 0.f};

  gload16(kbase,            &sK[0][(w * 16 + 0) * 64]);
  gload16(kbase + 8 * 2048, &sK[0][(w * 16 + 8) * 64]);
  gload16(vbase,            &sV[0][(w * 16 + 0) * 64]);
  gload16(vbase + 8 * 2048, &sV[0][(w * 16 + 8) * 64]);

  for (int t = 0; t < 32; ++t) {
    const int buf = t & 1;
    if (t + 1 < 32) {
      const int k0 = (t + 1) * 64;
      const int nb = buf ^ 1;
      gload16(kbase + (long)k0 * 2048,            &sK[nb][(w * 16 + 0) * 64]);
      gload16(kbase + (long)k0 * 2048 + 8 * 2048, &sK[nb][(w * 16 + 8) * 64]);
      gload16(vbase + k0,                         &sV[nb][(w * 16 + 0) * 64]);
      gload16(vbase + k0 + 8 * 2048,              &sV[nb][(w * 16 + 8) * 64]);
      wait_vm4();
    } else {
      wait_vm0();
    }
    sfence();
    rbar();
    sfence();
    const unsigned short* bK = sK[buf];
    const unsigned short* bV = sV[buf];

#pragma unroll
    for (int G = 0; G < 2; ++G) {
      f32x16 sacc = {};
      __builtin_amdgcn_s_setprio(1);
#pragma unroll
      for (int s = 0; s < 4; ++s) {
        const int key = G * 32 + l31;
        const int p   = (s * 2 + lh) ^ (key & 7);
        const bf16x8 kf = *(const bf16x8*)(bK + key * 64 + p * 8);
        sacc = __builtin_amdgcn_mfma_f32_32x32x16_bf16(kf, qf[s], sacc, 0, 0, 0);
      }
      __builtin_amdgcn_s_setprio(0);
      float e[16];
#pragma unroll
      for (int i = 0; i < 16; ++i) e[i] = __builtin_amdgcn_exp2f(sacc[i]);
#pragma unroll
      for (int i = 0; i < 8; ++i) {
        f32x2 pr = {e[2 * i], e[2 * i + 1]};
        lp2 += pr;
      }
      unsigned d[8];
#pragma unroll
      for (int i = 0; i < 8; ++i) d[i] = pack2bf(e[2 * i], e[2 * i + 1]);
      plswap(d[0], d[2]); plswap(d[1], d[3]);
      plswap(d[4], d[6]); plswap(d[5], d[7]);
      bf16x8 pp[2];
      pp[0] = frag4(d[0], d[1], d[2], d[3]);
      pp[1] = frag4(d[4], d[5], d[6], d[7]);
      __builtin_amdgcn_s_setprio(1);
#pragma unroll
      for (int sub = 0; sub < 2; ++sub) {
        const int gt  = (G * 2 + sub) * 2 + lh;
        const int d0r = l31, d1r = 32 + l31;
        const bf16x8 vf0 = *(const bf16x8*)(bV + d0r * 64 + ((gt ^ (d0r & 7))) * 8);
        const bf16x8 vf1 = *(const bf16x8*)(bV + d1r * 64 + ((gt ^ (d1r & 7))) * 8);
        oacc[0] = __builtin_amdgcn_mfma_f32_32x32x16_bf16(pp[sub], vf0, oacc[0], 0, 0, 0);
        oacc[1] = __builtin_amdgcn_mfma_f32_32x32x16_bf16(pp[sub], vf1, oacc[1], 0, 0, 0);
      }
      __builtin_amdgcn_s_setprio(0);
    }
    sfence();
    rbar();
  }

  const float lp = lp2.x + lp2.y;
  const float fs = lp + __shfl_xor(lp, 32);
  const float rc = 1.0f / fs;
#pragma unroll
  for (int r = 0; r < 16; ++r) {
    const int row = (r & 3) + 8 * (r >> 2) + 4 * lh;
    const float sc = __shfl(rc, row);
    const long base = (tokbase + qbase + row) * 1024 + hh * 64;
    attnb[base + l31]      = f2bf(oacc[0][r] * sc);
    attnb[base + 32 + l31] = f2bf(oacc[1][r] * sc);
  }
}

// ---------------------------------------------------------------------------
extern "C" void kernel_launch(void* const* d_in, const int* in_sizes, int n_in,
                              void* d_out, int out_size, void* d_ws, size_t ws_size,
                              hipStream_t stream) {
  const float* x    = (const float*)d_in[0];
  const float* wqkv = (const float*)d_in[1];
  const float* wout = (const float*)d_in[2];
  float* outp = (float*)d_out;

  unsigned short* xb    = (unsigned short*)d_ws;          // 8192*1024
  unsigned short* wqkvb = xb    + (long)NTOK * EMB;       // 3072*1024
  unsigned short* woutb = wqkvb + (long)FQKV * EMB;       // 1024*1024
  unsigned short* qkb   = woutb + (long)EMB * EMB;        // 8192*2048 (Q|K)
  unsigned short* vTb   = qkb   + (long)NTOK * 2048;      // 4*16*64*2048
  unsigned short* attnb = vTb   + (long)4 * 16 * 64 * TB; // 8192*1024

  cvt_kernel<<<12288, 256, 0, stream>>>(
      (const float4*)x, (const float4*)wqkv, (const float4*)wout,
      (ushort4*)xb, (ushort4*)wqkvb, (ushort4*)woutb);

  // QKV projection: best-measured 128^2 single-buffered structure,
  // 1536 blocks (6 rounds of 256 CUs, 4 blocks/CU co-resident)
  gemm_bt<0><<<dim3(24, 64), 256, 0, stream>>>(xb, wqkvb, EMB, qkb, vTb, nullptr);

  attn_kernel<<<dim3(64, 16), 256, 0, stream>>>(qkb, vTb, attnb);

  // output projection: same structure, 512 blocks
  gemm_bt<1><<<dim3(8, 64), 256, 0, stream>>>(attnb, woutb, EMB, nullptr, nullptr, outp);
}

// Round 7
// 268.963 us; speedup vs baseline: 1.1875x; 1.0015x over previous
//
#include <hip/hip_runtime.h>

#define DI __device__ __forceinline__

typedef float  f32x2  __attribute__((ext_vector_type(2)));
typedef float  f32x4  __attribute__((ext_vector_type(4)));
typedef float  f32x16 __attribute__((ext_vector_type(16)));
typedef __bf16 bf16x8 __attribute__((ext_vector_type(8)));
typedef unsigned u32x2 __attribute__((ext_vector_type(2)));
typedef unsigned u32x4 __attribute__((ext_vector_type(4)));

static constexpr int TB   = 2048;   // tokens per batch
static constexpr int NTOK = 8192;   // 4 * 2048
static constexpr int EMB  = 1024;
static constexpr int FQKV = 3072;

// RTNE float -> bf16 bits
DI unsigned short f2bf(float f) {
  union { float f; unsigned u; } v; v.f = f;
  unsigned r = v.u + 0x7FFFu + ((v.u >> 16) & 1u);
  return (unsigned short)(r >> 16);
}

DI unsigned pack2bf(float a, float b) {
#if __has_builtin(__builtin_amdgcn_cvt_pk_bf16_f32)
  typedef __bf16 bf16x2 __attribute__((ext_vector_type(2)));
  bf16x2 r = __builtin_amdgcn_cvt_pk_bf16_f32(a, b);
  return __builtin_bit_cast(unsigned, r);
#else
  unsigned ua = __builtin_bit_cast(unsigned, a) + 0x8000u;
  unsigned ub = __builtin_bit_cast(unsigned, b) + 0x8000u;
  return __builtin_amdgcn_perm(ub, ua, 0x07060302u);
#endif
}

DI void plswap(unsigned& a, unsigned& b) {
#if __has_builtin(__builtin_amdgcn_permlane32_swap)
  u32x2 r = __builtin_amdgcn_permlane32_swap(a, b, false, false);
  a = r.x; b = r.y;
#else
  const bool hi = (threadIdx.x & 32) != 0;
  unsigned ax = (unsigned)__shfl_xor((int)a, 32);
  unsigned bx = (unsigned)__shfl_xor((int)b, 32);
  unsigned na = hi ? bx : a;
  unsigned nb = hi ? b : ax;
  a = na; b = nb;
#endif
}

DI bf16x8 frag4(unsigned a, unsigned b, unsigned c, unsigned d) {
  u32x4 u = {a, b, c, d};
  return __builtin_bit_cast(bf16x8, u);
}

// async global->LDS, 16B per lane; LDS dest = wave-uniform base + lane*16
DI void gload16(const void* g, void* l) {
  __builtin_amdgcn_global_load_lds(
      (__attribute__((address_space(1))) void*)(g),
      (__attribute__((address_space(3))) void*)(l), 16, 0, 0);
}

DI void wait_vm4() { asm volatile("s_waitcnt vmcnt(4)" ::: "memory"); }
DI void wait_vm0() { asm volatile("s_waitcnt vmcnt(0)" ::: "memory"); }
DI void rbar()     { __builtin_amdgcn_s_barrier(); }
DI void sfence()   { __builtin_amdgcn_sched_barrier(0); }

// barrier with guaranteed pre-drain of this wave's outstanding DMA ops
DI void syncdrain() {
  __builtin_amdgcn_s_waitcnt(0);
  __syncthreads();
}

// ---------------- fp32 -> bf16 conversion for x, w_qkv, w_out ----------------
__global__ __launch_bounds__(256)
void cvt_kernel(const float4* __restrict__ x, const float4* __restrict__ wq,
                const float4* __restrict__ wo,
                ushort4* __restrict__ xb, ushort4* __restrict__ wqb,
                ushort4* __restrict__ wob) {
  const int i  = blockIdx.x * 256 + threadIdx.x;
  const int nx = NTOK * EMB / 4;
  const int nq = FQKV * EMB / 4;
  float4 v; ushort4* dst;
  if (i < nx)           { v = x[i];           dst = xb  + i; }
  else if (i < nx + nq) { v = wq[i - nx];     dst = wqb + (i - nx); }
  else                  { v = wo[i - nx - nq]; dst = wob + (i - nx - nq); }
  ushort4 p;
  p.x = f2bf(v.x); p.y = f2bf(v.y); p.z = f2bf(v.z); p.w = f2bf(v.w);
  *dst = p;
}

// ---------------- 256x128 bf16 QKV GEMM, 8 waves, single-buffered ------------
// r6 post-mortem: QKV at 128^2 moves 768MB through global_load_lds (A x24 +
// B x64 re-reads) = 14.7 B/cyc/CU — the byte volume, not the schedule, is the
// binder (all schedule variants moved the same bytes and all landed ~90us;
// 256^2 halved bytes but lost multi-block residency). This kernel hits the
// untested quadrant: bigger tile (256x128 -> 576MB, -25%) AND 2 blocks/CU
// (24KB LDS, <=128 VGPR via launch_bounds(512,4), 16 waves/CU). Per-wave
// instruction profile identical to the proven gemm_bt: 64x64 output,
// acc[4][4], 8 ds_read_b128 + 16 MFMA per K=32 iter, same verified swizzle.
// 768 blocks = exactly 3 per CU, balanced.
__global__ __launch_bounds__(512, 4)
void gemm_qkv(const unsigned short* __restrict__ A,
              const unsigned short* __restrict__ Bt,
              const int K,
              unsigned short* __restrict__ qk,
              unsigned short* __restrict__ vT) {
  __shared__ unsigned short sA[256 * 32];   // 16KB
  __shared__ unsigned short sB[128 * 32];   // 8KB
  const int tid  = threadIdx.x;
  const int w    = tid >> 6;          // 0..7
  const int l    = tid & 63;
  const int quad = l >> 4;
  const int lr   = l & 15;
  // XCD-aware bijective swizzle (nwg = 24*32 = 768, %8==0)
  const int nwg  = gridDim.x * gridDim.y;
  const int orig = blockIdx.y * gridDim.x + blockIdx.x;
  const int swzb = (orig & 7) * (nwg >> 3) + (orig >> 3);
  const int n0   = (swzb % gridDim.x) * 128;   // feature tile (24 tiles)
  const int m0   = (swzb / gridDim.x) * 256;   // token tile   (32 tiles)
  const int wm   = (w >> 1) * 64;     // 4 M-groups
  const int wn   = (w & 1) * 64;      // 2 N-groups

  f32x4 acc[4][4];
#pragma unroll
  for (int i = 0; i < 4; ++i)
#pragma unroll
    for (int j = 0; j < 4; ++j) acc[i][j] = {0.f, 0.f, 0.f, 0.f};

  // staging: same pattern as gemm_bt. One gload16 = 1024B = 16 rows of 64B.
  // LDS pos (row r, granule p) holds src granule p ^ ((r>>1)&3).
  const int srow = l >> 2;                    // 0..15
  const int sg   = (l & 3) ^ ((l >> 3) & 3);  // pre-swizzled src granule
  // A: wave w stages rows [w*32, w*32+32) via 2 gload16
  const unsigned short* gA = A  + (long)(m0 + w * 32 + srow) * K + sg * 8;
  // B: wave w stages rows [w*16, w*16+16) via 1 gload16
  const unsigned short* gB = Bt + (long)(n0 + w * 16 + srow) * K + sg * 8;
  unsigned short* lA = sA + w * 1024;
  unsigned short* lB = sB + w * 512;
  const int swz = (lr >> 1) & 3;

  for (int k0 = 0; k0 < K; k0 += 32) {
    gload16(gA + k0,          lA);
    gload16(gA + k0 + 16 * K, lA + 512);
    gload16(gB + k0,          lB);
    syncdrain();
    bf16x8 af[4], bfr[4];
#pragma unroll
    for (int rt = 0; rt < 4; ++rt)
      af[rt] = *(const bf16x8*)(sA + (wm + rt * 16 + lr) * 32 + (quad ^ swz) * 8);
#pragma unroll
    for (int ct = 0; ct < 4; ++ct)
      bfr[ct] = *(const bf16x8*)(sB + (wn + ct * 16 + lr) * 32 + (quad ^ swz) * 8);
#pragma unroll
    for (int rt = 0; rt < 4; ++rt)
#pragma unroll
      for (int ct = 0; ct < 4; ++ct)
        acc[rt][ct] = __builtin_amdgcn_mfma_f32_16x16x32_bf16(af[rt], bfr[ct],
                                                              acc[rt][ct], 0, 0, 0);
    __syncthreads();
  }

  // QKV epilogue: whole 128-col tile is on one side of 2048 (and of 1024)
  if (n0 < 2048) {
    const float qs = (n0 < 1024) ? 0.18033688011112042f : 1.0f;
#pragma unroll
    for (int rt = 0; rt < 4; ++rt) {
      const int row = m0 + wm + rt * 16 + quad * 4;
#pragma unroll
      for (int ct = 0; ct < 4; ++ct) {
        const int col = n0 + wn + ct * 16 + lr;
#pragma unroll
        for (int r = 0; r < 4; ++r)
          qk[(long)(row + r) * 2048 + col] = f2bf(acc[rt][ct][r] * qs);
      }
    }
  } else {
#pragma unroll
    for (int rt = 0; rt < 4; ++rt) {
      const int tok = m0 + wm + rt * 16 + quad * 4;
      const int bb  = tok >> 11, tt = tok & 2047;
#pragma unroll
      for (int ct = 0; ct < 4; ++ct) {
        const int fv = n0 - 2048 + wn + ct * 16 + lr;  // h*64+d
        ushort4 p;
        p.x = f2bf(acc[rt][ct][0]); p.y = f2bf(acc[rt][ct][1]);
        p.z = f2bf(acc[rt][ct][2]); p.w = f2bf(acc[rt][ct][3]);
        *(ushort4*)(vT + ((long)(bb * 1024 + fv)) * 2048 + tt) = p;
      }
    }
  }
}

// ---------------- 128x128 bf16 GEMM (output projection, frozen from r6) -----
__global__ __launch_bounds__(256, 4)
void gemm_bt(const unsigned short* __restrict__ A,
             const unsigned short* __restrict__ Bt,
             const int K,
             float* __restrict__ outp) {
  __shared__ unsigned short sA[128 * 32];
  __shared__ unsigned short sB[128 * 32];
  const int tid  = threadIdx.x;
  const int w    = tid >> 6;
  const int l    = tid & 63;
  const int quad = l >> 4;
  const int lr   = l & 15;
  const int nwg  = gridDim.x * gridDim.y;
  const int orig = blockIdx.y * gridDim.x + blockIdx.x;
  const int swzb = (orig & 7) * (nwg >> 3) + (orig >> 3);
  const int n0   = (swzb % gridDim.x) * 128;
  const int m0   = (swzb / gridDim.x) * 128;
  const int wm   = (w >> 1) * 64;
  const int wn   = (w & 1) * 64;

  f32x4 acc[4][4];
#pragma unroll
  for (int i = 0; i < 4; ++i)
#pragma unroll
    for (int j = 0; j < 4; ++j) acc[i][j] = {0.f, 0.f, 0.f, 0.f};

  const int srow = l >> 2;
  const int sg   = (l & 3) ^ ((l >> 3) & 3);
  const unsigned short* gA = A  + (long)(m0 + w * 32 + srow) * K + sg * 8;
  const unsigned short* gB = Bt + (long)(n0 + w * 32 + srow) * K + sg * 8;
  unsigned short* lA = sA + w * 1024;
  unsigned short* lB = sB + w * 1024;
  const int swz = (lr >> 1) & 3;

  for (int k0 = 0; k0 < K; k0 += 32) {
    gload16(gA + k0,          lA);
    gload16(gA + k0 + 16 * K, lA + 512);
    gload16(gB + k0,          lB);
    gload16(gB + k0 + 16 * K, lB + 512);
    syncdrain();
    bf16x8 af[4], bfr[4];
#pragma unroll
    for (int rt = 0; rt < 4; ++rt)
      af[rt] = *(const bf16x8*)(sA + (wm + rt * 16 + lr) * 32 + (quad ^ swz) * 8);
#pragma unroll
    for (int ct = 0; ct < 4; ++ct)
      bfr[ct] = *(const bf16x8*)(sB + (wn + ct * 16 + lr) * 32 + (quad ^ swz) * 8);
#pragma unroll
    for (int rt = 0; rt < 4; ++rt)
#pragma unroll
      for (int ct = 0; ct < 4; ++ct)
        acc[rt][ct] = __builtin_amdgcn_mfma_f32_16x16x32_bf16(af[rt], bfr[ct],
                                                              acc[rt][ct], 0, 0, 0);
    __syncthreads();
  }

#pragma unroll
  for (int rt = 0; rt < 4; ++rt) {
    const int row = m0 + wm + rt * 16 + quad * 4;
#pragma unroll
    for (int ct = 0; ct < 4; ++ct) {
      const int col = n0 + wn + ct * 16 + lr;
#pragma unroll
      for (int r = 0; r < 4; ++r)
        outp[(long)(row + r) * 1024 + col] = acc[rt][ct][r];
    }
  }
}

// ---------------- flash attention (frozen: 89.5us across r2-r6) -------------
__global__ __launch_bounds__(256, 4)
void attn_kernel(const unsigned short* __restrict__ qk,
                 const unsigned short* __restrict__ vT,
                 unsigned short* __restrict__ attnb) {
  __shared__ unsigned short sK[2][64 * 64];
  __shared__ unsigned short sV[2][64 * 64];
  const int tid = threadIdx.x;
  const int w   = tid >> 6;
  const int l   = tid & 63;
  const int l31 = l & 31;
  const int lh  = l >> 5;
  const int h8  = lh * 8;
  const int bh  = blockIdx.x;
  const int hh  = bh & 15;
  const long tokbase = (long)(bh >> 4) * TB;
  const int qbase = blockIdx.y * 128 + w * 32;

  bf16x8 qf[4];
  {
    const unsigned short* qptr = qk + (tokbase + qbase + l31) * 2048 + hh * 64 + h8;
#pragma unroll
    for (int s = 0; s < 4; ++s) qf[s] = *(const bf16x8*)(qptr + s * 16);
  }

  const int srow = l >> 3;
  const int g    = (l & 7) ^ srow;
  const unsigned short* kbase =
      qk + (tokbase + w * 16 + srow) * 2048 + 1024 + hh * 64 + g * 8;
  const unsigned short* vbase =
      vT + ((long)bh * 64 + w * 16 + srow) * 2048 + g * 8;

  f32x16 oacc[2] = {{}, {}};
  f32x2 lp2 = {0.f, 0.f};

  gload16(kbase,            &sK[0][(w * 16 + 0) * 64]);
  gload16(kbase + 8 * 2048, &sK[0][(w * 16 + 8) * 64]);
  gload16(vbase,            &sV[0][(w * 16 + 0) * 64]);
  gload16(vbase + 8 * 2048, &sV[0][(w * 16 + 8) * 64]);

  for (int t = 0; t < 32; ++t) {
    const int buf = t & 1;
    if (t + 1 < 32) {
      const int k0 = (t + 1) * 64;
      const int nb = buf ^ 1;
      gload16(kbase + (long)k0 * 2048,            &sK[nb][(w * 16 + 0) * 64]);
      gload16(kbase + (long)k0 * 2048 + 8 * 2048, &sK[nb][(w * 16 + 8) * 64]);
      gload16(vbase + k0,                         &sV[nb][(w * 16 + 0) * 64]);
      gload16(vbase + k0 + 8 * 2048,              &sV[nb][(w * 16 + 8) * 64]);
      wait_vm4();
    } else {
      wait_vm0();
    }
    sfence();
    rbar();
    sfence();
    const unsigned short* bK = sK[buf];
    const unsigned short* bV = sV[buf];

#pragma unroll
    for (int G = 0; G < 2; ++G) {
      f32x16 sacc = {};
      __builtin_amdgcn_s_setprio(1);
#pragma unroll
      for (int s = 0; s < 4; ++s) {
        const int key = G * 32 + l31;
        const int p   = (s * 2 + lh) ^ (key & 7);
        const bf16x8 kf = *(const bf16x8*)(bK + key * 64 + p * 8);
        sacc = __builtin_amdgcn_mfma_f32_32x32x16_bf16(kf, qf[s], sacc, 0, 0, 0);
      }
      __builtin_amdgcn_s_setprio(0);
      float e[16];
#pragma unroll
      for (int i = 0; i < 16; ++i) e[i] = __builtin_amdgcn_exp2f(sacc[i]);
#pragma unroll
      for (int i = 0; i < 8; ++i) {
        f32x2 pr = {e[2 * i], e[2 * i + 1]};
        lp2 += pr;
      }
      unsigned d[8];
#pragma unroll
      for (int i = 0; i < 8; ++i) d[i] = pack2bf(e[2 * i], e[2 * i + 1]);
      plswap(d[0], d[2]); plswap(d[1], d[3]);
      plswap(d[4], d[6]); plswap(d[5], d[7]);
      bf16x8 pp[2];
      pp[0] = frag4(d[0], d[1], d[2], d[3]);
      pp[1] = frag4(d[4], d[5], d[6], d[7]);
      __builtin_amdgcn_s_setprio(1);
#pragma unroll
      for (int sub = 0; sub < 2; ++sub) {
        const int gt  = (G * 2 + sub) * 2 + lh;
        const int d0r = l31, d1r = 32 + l31;
        const bf16x8 vf0 = *(const bf16x8*)(bV + d0r * 64 + ((gt ^ (d0r & 7))) * 8);
        const bf16x8 vf1 = *(const bf16x8*)(bV + d1r * 64 + ((gt ^ (d1r & 7))) * 8);
        oacc[0] = __builtin_amdgcn_mfma_f32_32x32x16_bf16(pp[sub], vf0, oacc[0], 0, 0, 0);
        oacc[1] = __builtin_amdgcn_mfma_f32_32x32x16_bf16(pp[sub], vf1, oacc[1], 0, 0, 0);
      }
      __builtin_amdgcn_s_setprio(0);
    }
    sfence();
    rbar();
  }

  const float lp = lp2.x + lp2.y;
  const float fs = lp + __shfl_xor(lp, 32);
  const float rc = 1.0f / fs;
#pragma unroll
  for (int r = 0; r < 16; ++r) {
    const int row = (r & 3) + 8 * (r >> 2) + 4 * lh;
    const float sc = __shfl(rc, row);
    const long base = (tokbase + qbase + row) * 1024 + hh * 64;
    attnb[base + l31]      = f2bf(oacc[0][r] * sc);
    attnb[base + 32 + l31] = f2bf(oacc[1][r] * sc);
  }
}

// ---------------------------------------------------------------------------
extern "C" void kernel_launch(void* const* d_in, const int* in_sizes, int n_in,
                              void* d_out, int out_size, void* d_ws, size_t ws_size,
                              hipStream_t stream) {
  const float* x    = (const float*)d_in[0];
  const float* wqkv = (const float*)d_in[1];
  const float* wout = (const float*)d_in[2];
  float* outp = (float*)d_out;

  unsigned short* xb    = (unsigned short*)d_ws;          // 8192*1024
  unsigned short* wqkvb = xb    + (long)NTOK * EMB;       // 3072*1024
  unsigned short* woutb = wqkvb + (long)FQKV * EMB;       // 1024*1024
  unsigned short* qkb   = woutb + (long)EMB * EMB;        // 8192*2048 (Q|K)
  unsigned short* vTb   = qkb   + (long)NTOK * 2048;      // 4*16*64*2048
  unsigned short* attnb = vTb   + (long)4 * 16 * 64 * TB; // 8192*1024

  cvt_kernel<<<12288, 256, 0, stream>>>(
      (const float4*)x, (const float4*)wqkv, (const float4*)wout,
      (ushort4*)xb, (ushort4*)wqkvb, (ushort4*)woutb);

  // QKV projection: 256x128 tiles, 768 blocks (3/CU, 2 resident), 576MB staged
  gemm_qkv<<<dim3(24, 32), 512, 0, stream>>>(xb, wqkvb, EMB, qkb, vTb);

  attn_kernel<<<dim3(64, 16), 256, 0, stream>>>(qkb, vTb, attnb);

  // output projection: frozen 128^2 structure, 512 blocks
  gemm_bt<<<dim3(8, 64), 256, 0, stream>>>(attnb, woutb, EMB, outp);
}

// Round 8
// 266.561 us; speedup vs baseline: 1.1982x; 1.0090x over previous
//
#include <hip/hip_runtime.h>

#define DI __device__ __forceinline__

typedef float  f32x2  __attribute__((ext_vector_type(2)));
typedef float  f32x4  __attribute__((ext_vector_type(4)));
typedef float  f32x16 __attribute__((ext_vector_type(16)));
typedef __bf16 bf16x8 __attribute__((ext_vector_type(8)));
typedef unsigned u32x2 __attribute__((ext_vector_type(2)));
typedef unsigned u32x4 __attribute__((ext_vector_type(4)));

static constexpr int TB   = 2048;   // tokens per batch
static constexpr int NTOK = 8192;   // 4 * 2048
static constexpr int EMB  = 1024;
static constexpr int FQKV = 3072;

// RTNE float -> bf16 bits
DI unsigned short f2bf(float f) {
  union { float f; unsigned u; } v; v.f = f;
  unsigned r = v.u + 0x7FFFu + ((v.u >> 16) & 1u);
  return (unsigned short)(r >> 16);
}

DI unsigned pack2bf(float a, float b) {
#if __has_builtin(__builtin_amdgcn_cvt_pk_bf16_f32)
  typedef __bf16 bf16x2 __attribute__((ext_vector_type(2)));
  bf16x2 r = __builtin_amdgcn_cvt_pk_bf16_f32(a, b);
  return __builtin_bit_cast(unsigned, r);
#else
  unsigned ua = __builtin_bit_cast(unsigned, a) + 0x8000u;
  unsigned ub = __builtin_bit_cast(unsigned, b) + 0x8000u;
  return __builtin_amdgcn_perm(ub, ua, 0x07060302u);
#endif
}

DI void plswap(unsigned& a, unsigned& b) {
#if __has_builtin(__builtin_amdgcn_permlane32_swap)
  u32x2 r = __builtin_amdgcn_permlane32_swap(a, b, false, false);
  a = r.x; b = r.y;
#else
  const bool hi = (threadIdx.x & 32) != 0;
  unsigned ax = (unsigned)__shfl_xor((int)a, 32);
  unsigned bx = (unsigned)__shfl_xor((int)b, 32);
  unsigned na = hi ? bx : a;
  unsigned nb = hi ? b : ax;
  a = na; b = nb;
#endif
}

DI bf16x8 frag4(unsigned a, unsigned b, unsigned c, unsigned d) {
  u32x4 u = {a, b, c, d};
  return __builtin_bit_cast(bf16x8, u);
}

// async global->LDS, 16B per lane; LDS dest = wave-uniform base + lane*16
DI void gload16(const void* g, void* l) {
  __builtin_amdgcn_global_load_lds(
      (__attribute__((address_space(1))) void*)(g),
      (__attribute__((address_space(3))) void*)(l), 16, 0, 0);
}

DI void wait_vm4() { asm volatile("s_waitcnt vmcnt(4)" ::: "memory"); }
DI void wait_vm0() { asm volatile("s_waitcnt vmcnt(0)" ::: "memory"); }
DI void rbar()     { __builtin_amdgcn_s_barrier(); }
DI void sfence()   { __builtin_amdgcn_sched_barrier(0); }

// barrier with guaranteed pre-drain of this wave's outstanding DMA ops
DI void syncdrain() {
  __builtin_amdgcn_s_waitcnt(0);
  __syncthreads();
}

// ---------------- fp32 -> bf16 conversion for x, w_qkv, w_out ----------------
// r8: grid-stride at 3072 blocks (was 12288 one-shot blocks)
__global__ __launch_bounds__(256)
void cvt_kernel(const float4* __restrict__ x, const float4* __restrict__ wq,
                const float4* __restrict__ wo,
                ushort4* __restrict__ xb, ushort4* __restrict__ wqb,
                ushort4* __restrict__ wob) {
  const int nx   = NTOK * EMB / 4;            // 2097152
  const int nq   = FQKV * EMB / 4;            // 786432
  const int ntot = nx + nq + EMB * EMB / 4;   // + 262144
  for (int i = blockIdx.x * 256 + threadIdx.x; i < ntot; i += gridDim.x * 256) {
    float4 v; ushort4* dst;
    if (i < nx)           { v = x[i];            dst = xb  + i; }
    else if (i < nx + nq) { v = wq[i - nx];      dst = wqb + (i - nx); }
    else                  { v = wo[i - nx - nq]; dst = wob + (i - nx - nq); }
    ushort4 p;
    p.x = f2bf(v.x); p.y = f2bf(v.y); p.z = f2bf(v.z); p.w = f2bf(v.w);
    *dst = p;
  }
}

// ---------------- 256x128 bf16 QKV GEMM (frozen from r7: best-equal) ---------
__global__ __launch_bounds__(512, 4)
void gemm_qkv(const unsigned short* __restrict__ A,
              const unsigned short* __restrict__ Bt,
              const int K,
              unsigned short* __restrict__ qk,
              unsigned short* __restrict__ vT) {
  __shared__ unsigned short sA[256 * 32];   // 16KB
  __shared__ unsigned short sB[128 * 32];   // 8KB
  const int tid  = threadIdx.x;
  const int w    = tid >> 6;          // 0..7
  const int l    = tid & 63;
  const int quad = l >> 4;
  const int lr   = l & 15;
  const int nwg  = gridDim.x * gridDim.y;
  const int orig = blockIdx.y * gridDim.x + blockIdx.x;
  const int swzb = (orig & 7) * (nwg >> 3) + (orig >> 3);
  const int n0   = (swzb % gridDim.x) * 128;
  const int m0   = (swzb / gridDim.x) * 256;
  const int wm   = (w >> 1) * 64;
  const int wn   = (w & 1) * 64;

  f32x4 acc[4][4];
#pragma unroll
  for (int i = 0; i < 4; ++i)
#pragma unroll
    for (int j = 0; j < 4; ++j) acc[i][j] = {0.f, 0.f, 0.f, 0.f};

  const int srow = l >> 2;
  const int sg   = (l & 3) ^ ((l >> 3) & 3);
  const unsigned short* gA = A  + (long)(m0 + w * 32 + srow) * K + sg * 8;
  const unsigned short* gB = Bt + (long)(n0 + w * 16 + srow) * K + sg * 8;
  unsigned short* lA = sA + w * 1024;
  unsigned short* lB = sB + w * 512;
  const int swz = (lr >> 1) & 3;

  for (int k0 = 0; k0 < K; k0 += 32) {
    gload16(gA + k0,          lA);
    gload16(gA + k0 + 16 * K, lA + 512);
    gload16(gB + k0,          lB);
    syncdrain();
    bf16x8 af[4], bfr[4];
#pragma unroll
    for (int rt = 0; rt < 4; ++rt)
      af[rt] = *(const bf16x8*)(sA + (wm + rt * 16 + lr) * 32 + (quad ^ swz) * 8);
#pragma unroll
    for (int ct = 0; ct < 4; ++ct)
      bfr[ct] = *(const bf16x8*)(sB + (wn + ct * 16 + lr) * 32 + (quad ^ swz) * 8);
#pragma unroll
    for (int rt = 0; rt < 4; ++rt)
#pragma unroll
      for (int ct = 0; ct < 4; ++ct)
        acc[rt][ct] = __builtin_amdgcn_mfma_f32_16x16x32_bf16(af[rt], bfr[ct],
                                                              acc[rt][ct], 0, 0, 0);
    __syncthreads();
  }

  if (n0 < 2048) {
    const float qs = (n0 < 1024) ? 0.18033688011112042f : 1.0f;
#pragma unroll
    for (int rt = 0; rt < 4; ++rt) {
      const int row = m0 + wm + rt * 16 + quad * 4;
#pragma unroll
      for (int ct = 0; ct < 4; ++ct) {
        const int col = n0 + wn + ct * 16 + lr;
#pragma unroll
        for (int r = 0; r < 4; ++r)
          qk[(long)(row + r) * 2048 + col] = f2bf(acc[rt][ct][r] * qs);
      }
    }
  } else {
#pragma unroll
    for (int rt = 0; rt < 4; ++rt) {
      const int tok = m0 + wm + rt * 16 + quad * 4;
      const int bb  = tok >> 11, tt = tok & 2047;
#pragma unroll
      for (int ct = 0; ct < 4; ++ct) {
        const int fv = n0 - 2048 + wn + ct * 16 + lr;  // h*64+d
        ushort4 p;
        p.x = f2bf(acc[rt][ct][0]); p.y = f2bf(acc[rt][ct][1]);
        p.z = f2bf(acc[rt][ct][2]); p.w = f2bf(acc[rt][ct][3]);
        *(ushort4*)(vT + ((long)(bb * 1024 + fv)) * 2048 + tt) = p;
      }
    }
  }
}

// ---------------- 128x64 bf16 out-projection GEMM, 4 blocks/CU ---------------
// r8: out-proj was the decomposition anomaly (~70us implied for 17.2 GF).
// Its 128^2 grid was 512 blocks = 2 blocks/CU resident — half the block-level
// concurrency that r6 proved is THE working mechanism for this loop structure.
// 128x64 tile -> grid (16,64) = 1024 blocks = 4/CU (12KB LDS, acc[4][2],
// ~85 VGPR). Extra A re-reads are fine: bytes proven non-binding (r7 null).
__global__ __launch_bounds__(256, 4)
void gemm_out(const unsigned short* __restrict__ A,
              const unsigned short* __restrict__ Bt,
              const int K,
              float* __restrict__ outp) {
  __shared__ unsigned short sA[128 * 32];   // 8KB
  __shared__ unsigned short sB[64 * 32];    // 4KB
  const int tid  = threadIdx.x;
  const int w    = tid >> 6;
  const int l    = tid & 63;
  const int quad = l >> 4;
  const int lr   = l & 15;
  const int nwg  = gridDim.x * gridDim.y;   // 1024, %8==0
  const int orig = blockIdx.y * gridDim.x + blockIdx.x;
  const int swzb = (orig & 7) * (nwg >> 3) + (orig >> 3);
  const int n0   = (swzb % gridDim.x) * 64;
  const int m0   = (swzb / gridDim.x) * 128;
  const int wm   = (w >> 1) * 64;   // 2 M-groups
  const int wn   = (w & 1) * 32;    // 2 N-groups

  f32x4 acc[4][2];
#pragma unroll
  for (int i = 0; i < 4; ++i)
#pragma unroll
    for (int j = 0; j < 2; ++j) acc[i][j] = {0.f, 0.f, 0.f, 0.f};

  const int srow = l >> 2;
  const int sg   = (l & 3) ^ ((l >> 3) & 3);
  const unsigned short* gA = A  + (long)(m0 + w * 32 + srow) * K + sg * 8;
  const unsigned short* gB = Bt + (long)(n0 + w * 16 + srow) * K + sg * 8;
  unsigned short* lA = sA + w * 1024;
  unsigned short* lB = sB + w * 512;
  const int swz = (lr >> 1) & 3;

  for (int k0 = 0; k0 < K; k0 += 32) {
    gload16(gA + k0,          lA);
    gload16(gA + k0 + 16 * K, lA + 512);
    gload16(gB + k0,          lB);
    syncdrain();
    bf16x8 af[4], bfr[2];
#pragma unroll
    for (int rt = 0; rt < 4; ++rt)
      af[rt] = *(const bf16x8*)(sA + (wm + rt * 16 + lr) * 32 + (quad ^ swz) * 8);
#pragma unroll
    for (int ct = 0; ct < 2; ++ct)
      bfr[ct] = *(const bf16x8*)(sB + (wn + ct * 16 + lr) * 32 + (quad ^ swz) * 8);
#pragma unroll
    for (int rt = 0; rt < 4; ++rt)
#pragma unroll
      for (int ct = 0; ct < 2; ++ct)
        acc[rt][ct] = __builtin_amdgcn_mfma_f32_16x16x32_bf16(af[rt], bfr[ct],
                                                              acc[rt][ct], 0, 0, 0);
    __syncthreads();
  }

#pragma unroll
  for (int rt = 0; rt < 4; ++rt) {
    const int row = m0 + wm + rt * 16 + quad * 4;
#pragma unroll
    for (int ct = 0; ct < 2; ++ct) {
      const int col = n0 + wn + ct * 16 + lr;
#pragma unroll
      for (int r = 0; r < 4; ++r)
        outp[(long)(row + r) * 1024 + col] = acc[rt][ct][r];
    }
  }
}

// ---------------- flash attention (frozen: ~91us across r2-r7) --------------
__global__ __launch_bounds__(256, 4)
void attn_kernel(const unsigned short* __restrict__ qk,
                 const unsigned short* __restrict__ vT,
                 unsigned short* __restrict__ attnb) {
  __shared__ unsigned short sK[2][64 * 64];
  __shared__ unsigned short sV[2][64 * 64];
  const int tid = threadIdx.x;
  const int w   = tid >> 6;
  const int l   = tid & 63;
  const int l31 = l & 31;
  const int lh  = l >> 5;
  const int h8  = lh * 8;
  const int bh  = blockIdx.x;
  const int hh  = bh & 15;
  const long tokbase = (long)(bh >> 4) * TB;
  const int qbase = blockIdx.y * 128 + w * 32;

  bf16x8 qf[4];
  {
    const unsigned short* qptr = qk + (tokbase + qbase + l31) * 2048 + hh * 64 + h8;
#pragma unroll
    for (int s = 0; s < 4; ++s) qf[s] = *(const bf16x8*)(qptr + s * 16);
  }

  const int srow = l >> 3;
  const int g    = (l & 7) ^ srow;
  const unsigned short* kbase =
      qk + (tokbase + w * 16 + srow) * 2048 + 1024 + hh * 64 + g * 8;
  const unsigned short* vbase =
      vT + ((long)bh * 64 + w * 16 + srow) * 2048 + g * 8;

  f32x16 oacc[2] = {{}, {}};
  f32x2 lp2 = {0.f, 0.f};

  gload16(kbase,            &sK[0][(w * 16 + 0) * 64]);
  gload16(kbase + 8 * 2048, &sK[0][(w * 16 + 8) * 64]);
  gload16(vbase,            &sV[0][(w * 16 + 0) * 64]);
  gload16(vbase + 8 * 2048, &sV[0][(w * 16 + 8) * 64]);

  for (int t = 0; t < 32; ++t) {
    const int buf = t & 1;
    if (t + 1 < 32) {
      const int k0 = (t + 1) * 64;
      const int nb = buf ^ 1;
      gload16(kbase + (long)k0 * 2048,            &sK[nb][(w * 16 + 0) * 64]);
      gload16(kbase + (long)k0 * 2048 + 8 * 2048, &sK[nb][(w * 16 + 8) * 64]);
      gload16(vbase + k0,                         &sV[nb][(w * 16 + 0) * 64]);
      gload16(vbase + k0 + 8 * 2048,              &sV[nb][(w * 16 + 8) * 64]);
      wait_vm4();
    } else {
      wait_vm0();
    }
    sfence();
    rbar();
    sfence();
    const unsigned short* bK = sK[buf];
    const unsigned short* bV = sV[buf];

#pragma unroll
    for (int G = 0; G < 2; ++G) {
      f32x16 sacc = {};
      __builtin_amdgcn_s_setprio(1);
#pragma unroll
      for (int s = 0; s < 4; ++s) {
        const int key = G * 32 + l31;
        const int p   = (s * 2 + lh) ^ (key & 7);
        const bf16x8 kf = *(const bf16x8*)(bK + key * 64 + p * 8);
        sacc = __builtin_amdgcn_mfma_f32_32x32x16_bf16(kf, qf[s], sacc, 0, 0, 0);
      }
      __builtin_amdgcn_s_setprio(0);
      float e[16];
#pragma unroll
      for (int i = 0; i < 16; ++i) e[i] = __builtin_amdgcn_exp2f(sacc[i]);
#pragma unroll
      for (int i = 0; i < 8; ++i) {
        f32x2 pr = {e[2 * i], e[2 * i + 1]};
        lp2 += pr;
      }
      unsigned d[8];
#pragma unroll
      for (int i = 0; i < 8; ++i) d[i] = pack2bf(e[2 * i], e[2 * i + 1]);
      plswap(d[0], d[2]); plswap(d[1], d[3]);
      plswap(d[4], d[6]); plswap(d[5], d[7]);
      bf16x8 pp[2];
      pp[0] = frag4(d[0], d[1], d[2], d[3]);
      pp[1] = frag4(d[4], d[5], d[6], d[7]);
      __builtin_amdgcn_s_setprio(1);
#pragma unroll
      for (int sub = 0; sub < 2; ++sub) {
        const int gt  = (G * 2 + sub) * 2 + lh;
        const int d0r = l31, d1r = 32 + l31;
        const bf16x8 vf0 = *(const bf16x8*)(bV + d0r * 64 + ((gt ^ (d0r & 7))) * 8);
        const bf16x8 vf1 = *(const bf16x8*)(bV + d1r * 64 + ((gt ^ (d1r & 7))) * 8);
        oacc[0] = __builtin_amdgcn_mfma_f32_32x32x16_bf16(pp[sub], vf0, oacc[0], 0, 0, 0);
        oacc[1] = __builtin_amdgcn_mfma_f32_32x32x16_bf16(pp[sub], vf1, oacc[1], 0, 0, 0);
      }
      __builtin_amdgcn_s_setprio(0);
    }
    sfence();
    rbar();
  }

  const float lp = lp2.x + lp2.y;
  const float fs = lp + __shfl_xor(lp, 32);
  const float rc = 1.0f / fs;
#pragma unroll
  for (int r = 0; r < 16; ++r) {
    const int row = (r & 3) + 8 * (r >> 2) + 4 * lh;
    const float sc = __shfl(rc, row);
    const long base = (tokbase + qbase + row) * 1024 + hh * 64;
    attnb[base + l31]      = f2bf(oacc[0][r] * sc);
    attnb[base + 32 + l31] = f2bf(oacc[1][r] * sc);
  }
}

// ---------------------------------------------------------------------------
extern "C" void kernel_launch(void* const* d_in, const int* in_sizes, int n_in,
                              void* d_out, int out_size, void* d_ws, size_t ws_size,
                              hipStream_t stream) {
  const float* x    = (const float*)d_in[0];
  const float* wqkv = (const float*)d_in[1];
  const float* wout = (const float*)d_in[2];
  float* outp = (float*)d_out;

  unsigned short* xb    = (unsigned short*)d_ws;          // 8192*1024
  unsigned short* wqkvb = xb    + (long)NTOK * EMB;       // 3072*1024
  unsigned short* woutb = wqkvb + (long)FQKV * EMB;       // 1024*1024
  unsigned short* qkb   = woutb + (long)EMB * EMB;        // 8192*2048 (Q|K)
  unsigned short* vTb   = qkb   + (long)NTOK * 2048;      // 4*16*64*2048
  unsigned short* attnb = vTb   + (long)4 * 16 * 64 * TB; // 8192*1024

  cvt_kernel<<<3072, 256, 0, stream>>>(
      (const float4*)x, (const float4*)wqkv, (const float4*)wout,
      (ushort4*)xb, (ushort4*)wqkvb, (ushort4*)woutb);

  // QKV projection: 256x128 tiles, 768 blocks (frozen from r7)
  gemm_qkv<<<dim3(24, 32), 512, 0, stream>>>(xb, wqkvb, EMB, qkb, vTb);

  attn_kernel<<<dim3(64, 16), 256, 0, stream>>>(qkb, vTb, attnb);

  // output projection: 128x64 tiles, 1024 blocks = 4 blocks/CU resident
  gemm_out<<<dim3(16, 64), 256, 0, stream>>>(attnb, woutb, EMB, outp);
}